// Round 7
// baseline (935.979 us; speedup 1.0000x reference)
//
#include <hip/hip_runtime.h>
#include <stdint.h>

#define K_DIM 1024
#define B_SZ 4
#define N_SEQ 2048
#define HEADS 16
#define DH 64
#define M_TOT (B_SZ * N_SEQ)  // 8192

typedef __bf16 bf16x8 __attribute__((ext_vector_type(8)));
typedef __bf16 bf16x4 __attribute__((ext_vector_type(4)));
typedef float f32x4 __attribute__((ext_vector_type(4)));
typedef short s16x4 __attribute__((ext_vector_type(4)));

typedef const uint32_t __attribute__((address_space(1))) gas_u32;
typedef uint32_t __attribute__((address_space(3))) las_u32;

#define CE_SCALE 0.1803368801f  // 0.125 * log2(e), folded into Q projection

__device__ __forceinline__ uint16_t f2bf(float f) {
  uint32_t u = __float_as_uint(f);
  u += 0x7FFFu + ((u >> 16) & 1u);  // round-nearest-even
  return (uint16_t)(u >> 16);
}

__device__ __forceinline__ void gld_lds16(const uint16_t* g, uint16_t* lds) {
  __builtin_amdgcn_global_load_lds((gas_u32*)g, (las_u32*)lds, 16, 0, 0);
}

// K=16 bf16 MFMA: A-operand layout (k = quad*4 + j) == our S^T C-layout.
#if defined(__has_builtin)
#if __has_builtin(__builtin_amdgcn_mfma_f32_16x16x16bf16_1k)
#define HAVE_MFMA16_BUILTIN 1
#endif
#endif

__device__ __forceinline__ f32x4 mfma16(bf16x4 a, bf16x4 b, f32x4 c) {
#ifdef HAVE_MFMA16_BUILTIN
  return __builtin_amdgcn_mfma_f32_16x16x16bf16_1k(
      __builtin_bit_cast(s16x4, a), __builtin_bit_cast(s16x4, b), c, 0, 0, 0);
#else
  f32x4 d;
  asm("v_mfma_f32_16x16x16_bf16 %0, %1, %2, %3"
      : "=v"(d)
      : "v"(a), "v"(b), "v"(c));
  return d;
#endif
}

// ---------------- fp32 -> bf16 convert (batched over 3 tensors) ----------------
__global__ __launch_bounds__(256) void conv_bf16_k(const float* __restrict__ s0,
                                                   const float* __restrict__ s1,
                                                   const float* __restrict__ s2,
                                                   uint16_t* __restrict__ dstbase, int n4) {
  const int z = blockIdx.y;
  const float* src = (z == 0) ? s0 : (z == 1) ? s1 : s2;
  uint16_t* dst = dstbase + (size_t)z * M_TOT * K_DIM;
  int i = blockIdx.x * blockDim.x + threadIdx.x;
  if (i < n4) {
    float4 v = ((const float4*)src)[i];
    ushort4 o;
    o.x = f2bf(v.x); o.y = f2bf(v.y); o.z = f2bf(v.z); o.w = f2bf(v.w);
    ((ushort4*)dst)[i] = o;
  }
}

// ------------- transpose + convert weights (batched over 4) ----------------------
__global__ __launch_bounds__(256) void transpose_conv(const float* __restrict__ s0,
                                                      const float* __restrict__ s1,
                                                      const float* __restrict__ s2,
                                                      const float* __restrict__ s3,
                                                      uint16_t* __restrict__ dstbase) {
  __shared__ float tile[32][33];
  const int z = blockIdx.z;
  const float* src = (z == 0) ? s0 : (z == 1) ? s1 : (z == 2) ? s2 : s3;
  uint16_t* dst = dstbase + (size_t)z * 1024 * 1024;
  const int tx = threadIdx.x, ty = threadIdx.y;
  const int bx = blockIdx.x * 32, by = blockIdx.y * 32;
#pragma unroll
  for (int i = 0; i < 32; i += 8)
    tile[ty + i][tx] = src[(size_t)(by + ty + i) * 1024 + bx + tx];
  __syncthreads();
#pragma unroll
  for (int i = 0; i < 32; i += 8)
    dst[(size_t)(bx + ty + i) * 1024 + by + tx] = f2bf(tile[tx][ty + i]);
}

// ---------------- GEMM: C[M,1024] = A[M,1024] @ B[1024,1024], BT[n][k] given -----
// XCD-locality swizzle: flat 1-D grid; XCD (bid&7) owns m-tiles [xcd*8, xcd*8+8),
// n fastest, z slowest -> per-XCD working set (A-slice 2MB + B 2MB) fits one L2.
// MODE 3: fused QKV (z=0 Q scaled -> [B,H,N,Dh]; z=1 K -> [B,H,N,Dh]; z=2 V -> [B,H,Dh,N])
// MODE 1: fp32 out row-major + bias (output projection), z=0 only.
template <int MODE>
__global__ __launch_bounds__(256, 2) void gemm_bf16(const uint16_t* __restrict__ A,
                                                    const uint16_t* __restrict__ BT,
                                                    void* __restrict__ Cout,
                                                    const float* __restrict__ bias) {
  __shared__ __align__(16) uint16_t As[128 * 32];
  __shared__ __align__(16) uint16_t Bs[128 * 32];
  const int tid = threadIdx.x;
  const int wave = tid >> 6, lane = tid & 63;
  const int g = lane >> 4, c16 = lane & 15;

  // swizzled block mapping
  const int bid = blockIdx.x;
  const int xcd = bid & 7;
  const int l = bid >> 3;
  const int z = (MODE == 3) ? (l >> 6) : 0;
  const int r = l & 63;
  const int n0 = (r & 7) * 128;
  const int m0 = (xcd * 8 + (r >> 3)) * 128;

  const int wr = wave >> 1, wc = wave & 1;
  float scale = 1.f;
  if (MODE == 3) {
    A += (size_t)z * M_TOT * K_DIM;
    BT += (size_t)z * 1024 * 1024;
    scale = (z == 0) ? CE_SCALE : 1.f;
  }

  const f32x4 fzero = {0.f, 0.f, 0.f, 0.f};
  f32x4 acc[4][4];
#pragma unroll
  for (int i = 0; i < 4; ++i)
#pragma unroll
    for (int j = 0; j < 4; ++j) acc[i][j] = fzero;

  const int srow = wave * 32 + (lane >> 2);
  const int scol = (lane & 3) * 8;
  const uint16_t* ag0 = A + (size_t)(m0 + srow) * K_DIM + scol;
  const uint16_t* ag1 = A + (size_t)(m0 + srow + 16) * K_DIM + scol;
  const uint16_t* bg0 = BT + (size_t)(n0 + srow) * K_DIM + scol;
  const uint16_t* bg1 = BT + (size_t)(n0 + srow + 16) * K_DIM + scol;
  uint16_t* la0 = &As[(wave * 32) * 32];
  uint16_t* la1 = &As[(wave * 32 + 16) * 32];
  uint16_t* lb0 = &Bs[(wave * 32) * 32];
  uint16_t* lb1 = &Bs[(wave * 32 + 16) * 32];

  for (int kt = 0; kt < K_DIM / 32; ++kt) {
    __syncthreads();
    gld_lds16(ag0 + kt * 32, la0);
    gld_lds16(ag1 + kt * 32, la1);
    gld_lds16(bg0 + kt * 32, lb0);
    gld_lds16(bg1 + kt * 32, lb1);
    __syncthreads();
    bf16x8 avec[4], bvec[4];
#pragma unroll
    for (int i = 0; i < 4; ++i)
      avec[i] = *(const bf16x8*)&As[(wr * 64 + i * 16 + c16) * 32 + g * 8];
#pragma unroll
    for (int j = 0; j < 4; ++j)
      bvec[j] = *(const bf16x8*)&Bs[(wc * 64 + j * 16 + c16) * 32 + g * 8];
#pragma unroll
    for (int i = 0; i < 4; ++i)
#pragma unroll
      for (int j = 0; j < 4; ++j)
        acc[i][j] = __builtin_amdgcn_mfma_f32_16x16x32_bf16(avec[i], bvec[j], acc[i][j], 0, 0, 0);
  }

#pragma unroll
  for (int i = 0; i < 4; ++i) {
#pragma unroll
    for (int j = 0; j < 4; ++j) {
      const int col = n0 + wc * 64 + j * 16 + c16;
      if (MODE == 3 && z == 2) {
        const int h = col >> 6, d = col & 63;
        const int row0 = m0 + wr * 64 + i * 16 + g * 4;
        const int b = row0 >> 11, n = row0 & 2047;
        ushort4 o;
        o.x = f2bf(acc[i][j][0]); o.y = f2bf(acc[i][j][1]);
        o.z = f2bf(acc[i][j][2]); o.w = f2bf(acc[i][j][3]);
        *(ushort4*)&((uint16_t*)Cout)[(size_t)2 * M_TOT * 1024 +
                                      (((size_t)(b * HEADS + h)) * DH + d) * N_SEQ + n] = o;
      } else {
#pragma unroll
        for (int r2 = 0; r2 < 4; ++r2) {
          const int row = m0 + wr * 64 + i * 16 + g * 4 + r2;
          if (MODE == 3) {
            const int b = row >> 11, n = row & 2047;
            const int h = col >> 6, d = col & 63;
            ((uint16_t*)Cout)[(size_t)z * M_TOT * 1024 +
                              (((size_t)(b * HEADS + h)) * N_SEQ + n) * DH + d] =
                f2bf(acc[i][j][r2] * scale);
          } else {
            ((float*)Cout)[(size_t)row * 1024 + col] = acc[i][j][r2] + bias[col];
          }
        }
      }
    }
  }
}

// ---------------- flash attention v7: in-block KV-split ----------------
// Block = 4 waves: (qhalf = wave&1) x (khalf = wave>>1). Each wave: 64 q-rows,
// 16 of 32 key-tiles. Grid 1024 -> 4 blocks/CU -> 4 waves/SIMD (needs VGPR<=128).
// Unnormalized softmax => partial (O, l) combine additively through LDS at end.
// Staging via global_load_lds with XOR swizzle applied to the per-lane SOURCE
// address (dest must be linear base + lane*16); fragment reads use the same
// (chunk ^ row&7) swizzle as before -> conflict-free, zero prefetch VGPRs.
__global__ __launch_bounds__(256, 4) void attention_k(const uint16_t* __restrict__ qm,
                                                      const uint16_t* __restrict__ km,
                                                      const uint16_t* __restrict__ vtm,
                                                      uint16_t* __restrict__ om) {
  // union: staging K[2][4096]+V[2][4096] bf16 (32KB)  |  combine O[2][64][68] f32 + l[2][4][64]
  __shared__ __align__(16) char smem[36864];
  uint16_t* KsB = (uint16_t*)smem;         // [2][4096]
  uint16_t* VsB = (uint16_t*)smem + 8192;  // [2][4096]

  const int tid = threadIdx.x;
  const int wave = tid >> 6, lane = tid & 63;
  const int g = lane >> 4, c16 = lane & 15;
  const int qhalf = wave & 1, khalf = wave >> 1;

  const int bid = blockIdx.x;
  const int xcd = bid & 7;
  const int l0 = bid >> 3;
  const int bh = xcd * 8 + (l0 & 7);
  const int qblk = l0 >> 3;  // 0..15
  const int b = bh >> 4, h = bh & 15;
  const int q0 = qblk * 128 + qhalf * 64;

  const uint16_t* qbase = qm + (size_t)bh * N_SEQ * DH;
  const uint16_t* kbase = km + (size_t)bh * N_SEQ * DH;
  const uint16_t* vbase = vtm + (size_t)bh * DH * N_SEQ;

  uint16_t* Ksp = KsB + khalf * 4096;
  uint16_t* Vsp = VsB + khalf * 4096;

  // Q as MFMA B-fragments (col = qrow = c16, k = d), straight from global
  bf16x8 qf[4][2];
#pragma unroll
  for (int qc = 0; qc < 4; ++qc) {
    const uint16_t* qp = qbase + (size_t)(q0 + qc * 16 + c16) * DH + g * 8;
    qf[qc][0] = *(const bf16x8*)qp;
    qf[qc][1] = *(const bf16x8*)(qp + 32);
  }

  const f32x4 fz = {0.f, 0.f, 0.f, 0.f};
  f32x4 oacc[4][4];
#pragma unroll
  for (int qc = 0; qc < 4; ++qc)
#pragma unroll
    for (int jt = 0; jt < 4; ++jt) oacc[qc][jt] = fz;
  float l[4] = {0.f, 0.f, 0.f, 0.f};

  const int sw = c16 & 7;  // XOR swizzle key for fragment reads

  // staging source offsets (swizzle folded into the per-lane global address)
  const int rr8 = lane >> 3, cc = lane & 7;
  const int chp = (cc ^ rr8) << 3;  // swizzled chunk start (elements)

  for (int tt = 0; tt < 16; ++tt) {
    const int t = khalf * 16 + tt;
    __syncthreads();  // all waves done reading previous tile
#pragma unroll
    for (int jj = 0; jj < 4; ++jj) {
      const int j = qhalf * 4 + jj;  // 8-row slab index within the 64-row tile
      const int row = j * 8 + rr8;
      gld_lds16(kbase + (size_t)t * 4096 + row * 64 + chp, Ksp + j * 512);
      gld_lds16(vbase + (size_t)row * N_SEQ + t * 64 + chp, Vsp + j * 512);
    }
    __syncthreads();  // __syncthreads drains vmcnt -> tiles visible

#pragma unroll
    for (int kt = 0; kt < 4; ++kt) {
      const int krow = kt * 16 + c16;
      bf16x8 kf0 = *(const bf16x8*)&Ksp[krow * 64 + ((g ^ sw) << 3)];
      bf16x8 kf1 = *(const bf16x8*)&Ksp[krow * 64 + (((4 + g) ^ sw) << 3)];
      bf16x4 pk[4];
#pragma unroll
      for (int qc = 0; qc < 4; ++qc) {
        f32x4 z = fz;
        z = __builtin_amdgcn_mfma_f32_16x16x32_bf16(kf0, qf[qc][0], z, 0, 0, 0);
        z = __builtin_amdgcn_mfma_f32_16x16x32_bf16(kf1, qf[qc][1], z, 0, 0, 0);
        f32x4 pv;
        pv[0] = __builtin_amdgcn_exp2f(z[0]);
        pv[1] = __builtin_amdgcn_exp2f(z[1]);
        pv[2] = __builtin_amdgcn_exp2f(z[2]);
        pv[3] = __builtin_amdgcn_exp2f(z[3]);
        l[qc] += (pv[0] + pv[1]) + (pv[2] + pv[3]);
        pk[qc] = __builtin_convertvector(pv, bf16x4);
      }
      // PV: 16 keys via K=16 MFMA; P regs already in A-layout.
#pragma unroll
      for (int jt = 0; jt < 4; ++jt) {
        bf16x4 vb = *(const bf16x4*)&Vsp[(jt * 16 + c16) * 64 +
                                         (((kt * 2 + (g >> 1)) ^ sw) << 3) + (g & 1) * 4];
#pragma unroll
        for (int qc = 0; qc < 4; ++qc) oacc[qc][jt] = mfma16(pk[qc], vb, oacc[qc][jt]);
      }
    }
  }

  // ---- combine the two key-halves through LDS (unnormalized => additive) ----
  __syncthreads();
  float* obuf = (float*)smem;                // [2][64][68]
  float* lbuf = (float*)(smem + 34816);      // [2][4][64]
  if (khalf == 1) {
#pragma unroll
    for (int qc = 0; qc < 4; ++qc) {
#pragma unroll
      for (int jt = 0; jt < 4; ++jt)
#pragma unroll
        for (int rr = 0; rr < 4; ++rr)
          obuf[qhalf * 4352 + (qc * 16 + g * 4 + rr) * 68 + jt * 16 + c16] = oacc[qc][jt][rr];
      lbuf[qhalf * 256 + qc * 64 + lane] = l[qc];
    }
  }
  __syncthreads();
  if (khalf == 0) {
#pragma unroll
    for (int qc = 0; qc < 4; ++qc) {
      l[qc] += lbuf[qhalf * 256 + qc * 64 + lane];
      l[qc] += __shfl_xor(l[qc], 16);
      l[qc] += __shfl_xor(l[qc], 32);
#pragma unroll
      for (int jt = 0; jt < 4; ++jt)
#pragma unroll
        for (int rr = 0; rr < 4; ++rr)
          oacc[qc][jt][rr] += obuf[qhalf * 4352 + (qc * 16 + g * 4 + rr) * 68 + jt * 16 + c16];
    }
    // epilogue: normalize, write O to [b][n][h*64+d] bf16
#pragma unroll
    for (int qc = 0; qc < 4; ++qc) {
#pragma unroll
      for (int r = 0; r < 4; ++r) {
        const float lr = __shfl(l[qc], g * 4 + r, 16);
        const float inv = 1.f / lr;
        const int row = q0 + qc * 16 + g * 4 + r;
        const size_t base = ((size_t)b * N_SEQ + row) * 1024 + h * 64;
#pragma unroll
        for (int jt = 0; jt < 4; ++jt)
          om[base + jt * 16 + c16] = f2bf(oacc[qc][jt][r] * inv);
      }
    }
  }
}

// ---------------- LayerNorm + residual ----------------
__global__ __launch_bounds__(256) void ln_res_k(const float* __restrict__ proj,
                                                const float* __restrict__ query,
                                                const float* __restrict__ gamma,
                                                const float* __restrict__ beta,
                                                float* __restrict__ out) {
  const int row = blockIdx.x;
  const int tid = threadIdx.x;
  const size_t base = (size_t)row * 1024 + tid * 4;
  float4 v = *(const float4*)(proj + base);
  float s = v.x + v.y + v.z + v.w;
  float s2 = v.x * v.x + v.y * v.y + v.z * v.z + v.w * v.w;
#pragma unroll
  for (int off = 1; off < 64; off <<= 1) {
    s += __shfl_xor(s, off);
    s2 += __shfl_xor(s2, off);
  }
  __shared__ float red[8];
  const int wave = tid >> 6, lane = tid & 63;
  if (lane == 0) { red[wave] = s; red[4 + wave] = s2; }
  __syncthreads();
  s = red[0] + red[1] + red[2] + red[3];
  s2 = red[4] + red[5] + red[6] + red[7];
  const float mu = s * (1.f / 1024.f);
  const float var = fmaxf(s2 * (1.f / 1024.f) - mu * mu, 0.f);
  const float rstd = rsqrtf(var + 1e-5f);
  float4 gq = *(const float4*)(gamma + tid * 4);
  float4 bq = *(const float4*)(beta + tid * 4);
  float4 qq = *(const float4*)(query + base);
  float4 o;
  o.x = (v.x - mu) * rstd * gq.x + bq.x + qq.x;
  o.y = (v.y - mu) * rstd * gq.y + bq.y + qq.y;
  o.z = (v.z - mu) * rstd * gq.z + bq.z + qq.z;
  o.w = (v.w - mu) * rstd * gq.w + bq.w + qq.w;
  *(float4*)(out + base) = o;
}

extern "C" void kernel_launch(void* const* d_in, const int* in_sizes, int n_in,
                              void* d_out, int out_size, void* d_ws, size_t ws_size,
                              hipStream_t stream) {
  (void)in_sizes; (void)n_in; (void)out_size; (void)ws_size;
  const float* query = (const float*)d_in[0];
  const float* key_ = (const float*)d_in[1];
  const float* value = (const float*)d_in[2];
  const float* Wq = (const float*)d_in[3];
  const float* Wk = (const float*)d_in[4];
  const float* Wv = (const float*)d_in[5];
  const float* Wo = (const float*)d_in[6];
  const float* bo = (const float*)d_in[7];
  const float* gamma = (const float*)d_in[8];
  const float* beta = (const float*)d_in[9];
  float* out = (float*)d_out;

  const size_t NELEM = (size_t)M_TOT * 1024;  // 8388608
  uint16_t* wsp = (uint16_t*)d_ws;
  uint16_t* WqT = wsp;                   // 4 x 1M bf16 (Wq,Wk,Wv,Wo contiguous)
  uint16_t* WoT = WqT + 3 * 1024 * 1024;
  uint16_t* xq = WqT + 4 * 1024 * 1024;  // xq,xk,xv contiguous (3 x NELEM)
  uint16_t* qb = xq + 3 * NELEM;         // qb,kb,vt contiguous (z * NELEM)
  uint16_t* attnO = xq;                  // alias: xq dead after QKV-GEMM
  float* proj = (float*)(xq + NELEM);    // alias: xk+xv dead after QKV-GEMM (32MB)

  const int n4 = (int)(NELEM / 4);
  conv_bf16_k<<<dim3(8192, 3), 256, 0, stream>>>(query, key_, value, xq, n4);

  transpose_conv<<<dim3(32, 32, 4), dim3(32, 8), 0, stream>>>(Wq, Wk, Wv, Wo, WqT);

  gemm_bf16<3><<<1536, 256, 0, stream>>>(xq, WqT, qb, nullptr);

  attention_k<<<1024, 256, 0, stream>>>(qb, qb + NELEM, qb + 2 * NELEM, attnO);

  gemm_bf16<1><<<512, 256, 0, stream>>>(attnO, WoT, proj, bo);

  ln_res_k<<<8192, 256, 0, stream>>>(proj, query, gamma, beta, out);
}

// Round 8
// 367.417 us; speedup vs baseline: 2.5475x; 2.5475x over previous
//
#include <hip/hip_runtime.h>
#include <stdint.h>

#define K_DIM 1024
#define B_SZ 4
#define N_SEQ 2048
#define HEADS 16
#define DH 64
#define M_TOT (B_SZ * N_SEQ)  // 8192

typedef __bf16 bf16x8 __attribute__((ext_vector_type(8)));
typedef __bf16 bf16x4 __attribute__((ext_vector_type(4)));
typedef float f32x4 __attribute__((ext_vector_type(4)));
typedef float f32x8 __attribute__((ext_vector_type(8)));
typedef short s16x4 __attribute__((ext_vector_type(4)));

typedef const uint32_t __attribute__((address_space(1))) gas_u32;
typedef uint32_t __attribute__((address_space(3))) las_u32;

#define CE_SCALE 0.1803368801f  // 0.125 * log2(e), folded into Q projection

__device__ __forceinline__ uint16_t f2bf(float f) {
  uint32_t u = __float_as_uint(f);
  u += 0x7FFFu + ((u >> 16) & 1u);  // round-nearest-even
  return (uint16_t)(u >> 16);
}

__device__ __forceinline__ void gld_lds16(const uint16_t* g, uint16_t* lds) {
  __builtin_amdgcn_global_load_lds((gas_u32*)g, (las_u32*)lds, 16, 0, 0);
}

// K=16 bf16 MFMA: A-operand layout (k = quad*4 + j) == our S^T C-layout.
#if defined(__has_builtin)
#if __has_builtin(__builtin_amdgcn_mfma_f32_16x16x16bf16_1k)
#define HAVE_MFMA16_BUILTIN 1
#endif
#endif

__device__ __forceinline__ f32x4 mfma16(bf16x4 a, bf16x4 b, f32x4 c) {
#ifdef HAVE_MFMA16_BUILTIN
  return __builtin_amdgcn_mfma_f32_16x16x16bf16_1k(
      __builtin_bit_cast(s16x4, a), __builtin_bit_cast(s16x4, b), c, 0, 0, 0);
#else
  f32x4 d;
  asm("v_mfma_f32_16x16x16_bf16 %0, %1, %2, %3"
      : "=v"(d)
      : "v"(a), "v"(b), "v"(c));
  return d;
#endif
}

// ------------- transpose + convert weights (batched over 4) ----------------------
__global__ __launch_bounds__(256) void transpose_conv(const float* __restrict__ s0,
                                                      const float* __restrict__ s1,
                                                      const float* __restrict__ s2,
                                                      const float* __restrict__ s3,
                                                      uint16_t* __restrict__ dstbase) {
  __shared__ float tile[32][33];
  const int z = blockIdx.z;
  const float* src = (z == 0) ? s0 : (z == 1) ? s1 : (z == 2) ? s2 : s3;
  uint16_t* dst = dstbase + (size_t)z * 1024 * 1024;
  const int tx = threadIdx.x, ty = threadIdx.y;
  const int bx = blockIdx.x * 32, by = blockIdx.y * 32;
#pragma unroll
  for (int i = 0; i < 32; i += 8)
    tile[ty + i][tx] = src[(size_t)(by + ty + i) * 1024 + bx + tx];
  __syncthreads();
#pragma unroll
  for (int i = 0; i < 32; i += 8)
    dst[(size_t)(bx + ty + i) * 1024 + by + tx] = f2bf(tile[tx][ty + i]);
}

// ---------------- fused QKV GEMM with in-kernel fp32->bf16 A conversion ----------
// C_z[M,1024] = cvt_bf16(A_z[M,1024]) @ B_z, A_z = {query,key_,value} fp32.
// A staged via VGPR-pipelined f32x8 loads + cvt + ds_write_b128 (reproduces the
// exact LDS layout global_load_lds produced); B via global_load_lds (bf16).
// XCD swizzle: XCD (bid&7) owns m-tiles [xcd*8, xcd*8+8); n fastest, z slowest.
// z=0: Q scaled by CE -> [B,H,N,Dh]; z=1: K -> [B,H,N,Dh]; z=2: V -> [B,H,Dh,N].
__global__ __launch_bounds__(256, 2) void gemm_qkv(const float* __restrict__ Aq,
                                                   const float* __restrict__ Ak,
                                                   const float* __restrict__ Av,
                                                   const uint16_t* __restrict__ BT,
                                                   uint16_t* __restrict__ Cout) {
  __shared__ __align__(16) uint16_t As[128 * 32];
  __shared__ __align__(16) uint16_t Bs[128 * 32];
  const int tid = threadIdx.x;
  const int wave = tid >> 6, lane = tid & 63;
  const int g = lane >> 4, c16 = lane & 15;

  const int bid = blockIdx.x;
  const int xcd = bid & 7;
  const int l = bid >> 3;
  const int z = l >> 6;
  const int r = l & 63;
  const int n0 = (r & 7) * 128;
  const int m0 = (xcd * 8 + (r >> 3)) * 128;

  const int wr = wave >> 1, wc = wave & 1;
  const float* A = (z == 0) ? Aq : (z == 1) ? Ak : Av;
  const uint16_t* Bz = BT + (size_t)z * 1024 * 1024;
  const float scale = (z == 0) ? CE_SCALE : 1.f;

  const f32x4 fzero = {0.f, 0.f, 0.f, 0.f};
  f32x4 acc[4][4];
#pragma unroll
  for (int i = 0; i < 4; ++i)
#pragma unroll
    for (int j = 0; j < 4; ++j) acc[i][j] = fzero;

  const int srow = wave * 32 + (lane >> 2);
  const int scol = (lane & 3) * 8;
  const float* ag0 = A + (size_t)(m0 + srow) * K_DIM + scol;
  const float* ag1 = A + (size_t)(m0 + srow + 16) * K_DIM + scol;
  const uint16_t* bg0 = Bz + (size_t)(n0 + srow) * K_DIM + scol;
  const uint16_t* bg1 = Bz + (size_t)(n0 + srow + 16) * K_DIM + scol;
  uint16_t* lb0 = &Bs[(wave * 32) * 32];
  uint16_t* lb1 = &Bs[(wave * 32 + 16) * 32];
  uint16_t* la0 = &As[srow * 32 + scol];
  uint16_t* la1 = &As[(srow + 16) * 32 + scol];

  // prefetch A regs for kt=0
  f32x4 ar0, ar1, ar2, ar3;
  ar0 = *(const f32x4*)(ag0);
  ar1 = *(const f32x4*)(ag0 + 4);
  ar2 = *(const f32x4*)(ag1);
  ar3 = *(const f32x4*)(ag1 + 4);

  for (int kt = 0; kt < K_DIM / 32; ++kt) {
    __syncthreads();  // all waves done reading previous LDS tiles
    // cvt + store A tile (auto-waits on the prefetch loads)
    {
      f32x8 f0 = __builtin_shufflevector(ar0, ar1, 0, 1, 2, 3, 4, 5, 6, 7);
      f32x8 f1 = __builtin_shufflevector(ar2, ar3, 0, 1, 2, 3, 4, 5, 6, 7);
      *(bf16x8*)la0 = __builtin_convertvector(f0, bf16x8);
      *(bf16x8*)la1 = __builtin_convertvector(f1, bf16x8);
    }
    gld_lds16(bg0 + kt * 32, lb0);
    gld_lds16(bg1 + kt * 32, lb1);
    __syncthreads();  // drains B gld + A ds_writes

    // issue next A loads: in flight across the MFMA stretch
    if (kt < K_DIM / 32 - 1) {
      const int ko = (kt + 1) * 32;
      ar0 = *(const f32x4*)(ag0 + ko);
      ar1 = *(const f32x4*)(ag0 + ko + 4);
      ar2 = *(const f32x4*)(ag1 + ko);
      ar3 = *(const f32x4*)(ag1 + ko + 4);
    }

    bf16x8 avec[4], bvec[4];
#pragma unroll
    for (int i = 0; i < 4; ++i)
      avec[i] = *(const bf16x8*)&As[(wr * 64 + i * 16 + c16) * 32 + g * 8];
#pragma unroll
    for (int j = 0; j < 4; ++j)
      bvec[j] = *(const bf16x8*)&Bs[(wc * 64 + j * 16 + c16) * 32 + g * 8];
#pragma unroll
    for (int i = 0; i < 4; ++i)
#pragma unroll
      for (int j = 0; j < 4; ++j)
        acc[i][j] = __builtin_amdgcn_mfma_f32_16x16x32_bf16(avec[i], bvec[j], acc[i][j], 0, 0, 0);
  }

#pragma unroll
  for (int i = 0; i < 4; ++i) {
#pragma unroll
    for (int j = 0; j < 4; ++j) {
      const int col = n0 + wc * 64 + j * 16 + c16;
      if (z == 2) {
        // V^T layout [b*16+h][d][n]; rows g*4+r2 are 4 consecutive n -> 8B store
        const int h = col >> 6, d = col & 63;
        const int row0 = m0 + wr * 64 + i * 16 + g * 4;
        const int b = row0 >> 11, n = row0 & 2047;
        ushort4 o;
        o.x = f2bf(acc[i][j][0]); o.y = f2bf(acc[i][j][1]);
        o.z = f2bf(acc[i][j][2]); o.w = f2bf(acc[i][j][3]);
        *(ushort4*)&Cout[(size_t)2 * M_TOT * 1024 +
                         (((size_t)(b * HEADS + h)) * DH + d) * N_SEQ + n] = o;
      } else {
#pragma unroll
        for (int r2 = 0; r2 < 4; ++r2) {
          const int row = m0 + wr * 64 + i * 16 + g * 4 + r2;
          const int b = row >> 11, n = row & 2047;
          const int h = col >> 6, d = col & 63;
          Cout[(size_t)z * M_TOT * 1024 + (((size_t)(b * HEADS + h)) * N_SEQ + n) * DH + d] =
              f2bf(acc[i][j][r2] * scale);
        }
      }
    }
  }
}

// ---------------- output projection GEMM (bf16 A via global_load_lds) -----------
// proj[M,1024] = attnO[M,1024] @ Wo + bias, fp32 out. XCD swizzle as above.
__global__ __launch_bounds__(256, 2) void gemm_out(const uint16_t* __restrict__ A,
                                                   const uint16_t* __restrict__ BT,
                                                   float* __restrict__ Cout,
                                                   const float* __restrict__ bias) {
  __shared__ __align__(16) uint16_t As[128 * 32];
  __shared__ __align__(16) uint16_t Bs[128 * 32];
  const int tid = threadIdx.x;
  const int wave = tid >> 6, lane = tid & 63;
  const int g = lane >> 4, c16 = lane & 15;

  const int bid = blockIdx.x;
  const int xcd = bid & 7;
  const int l = bid >> 3;
  const int n0 = (l & 7) * 128;
  const int m0 = (xcd * 8 + (l >> 3)) * 128;
  const int wr = wave >> 1, wc = wave & 1;

  const f32x4 fzero = {0.f, 0.f, 0.f, 0.f};
  f32x4 acc[4][4];
#pragma unroll
  for (int i = 0; i < 4; ++i)
#pragma unroll
    for (int j = 0; j < 4; ++j) acc[i][j] = fzero;

  const int srow = wave * 32 + (lane >> 2);
  const int scol = (lane & 3) * 8;
  const uint16_t* ag0 = A + (size_t)(m0 + srow) * K_DIM + scol;
  const uint16_t* ag1 = A + (size_t)(m0 + srow + 16) * K_DIM + scol;
  const uint16_t* bg0 = BT + (size_t)(n0 + srow) * K_DIM + scol;
  const uint16_t* bg1 = BT + (size_t)(n0 + srow + 16) * K_DIM + scol;
  uint16_t* la0 = &As[(wave * 32) * 32];
  uint16_t* la1 = &As[(wave * 32 + 16) * 32];
  uint16_t* lb0 = &Bs[(wave * 32) * 32];
  uint16_t* lb1 = &Bs[(wave * 32 + 16) * 32];

  for (int kt = 0; kt < K_DIM / 32; ++kt) {
    __syncthreads();
    gld_lds16(ag0 + kt * 32, la0);
    gld_lds16(ag1 + kt * 32, la1);
    gld_lds16(bg0 + kt * 32, lb0);
    gld_lds16(bg1 + kt * 32, lb1);
    __syncthreads();
    bf16x8 avec[4], bvec[4];
#pragma unroll
    for (int i = 0; i < 4; ++i)
      avec[i] = *(const bf16x8*)&As[(wr * 64 + i * 16 + c16) * 32 + g * 8];
#pragma unroll
    for (int j = 0; j < 4; ++j)
      bvec[j] = *(const bf16x8*)&Bs[(wc * 64 + j * 16 + c16) * 32 + g * 8];
#pragma unroll
    for (int i = 0; i < 4; ++i)
#pragma unroll
      for (int j = 0; j < 4; ++j)
        acc[i][j] = __builtin_amdgcn_mfma_f32_16x16x32_bf16(avec[i], bvec[j], acc[i][j], 0, 0, 0);
  }

#pragma unroll
  for (int i = 0; i < 4; ++i) {
#pragma unroll
    for (int j = 0; j < 4; ++j) {
      const int col = n0 + wc * 64 + j * 16 + c16;
#pragma unroll
      for (int r2 = 0; r2 < 4; ++r2) {
        const int row = m0 + wr * 64 + i * 16 + g * 4 + r2;
        Cout[(size_t)row * 1024 + col] = acc[i][j][r2] + bias[col];
      }
    }
  }
}

// ---------------- flash attention (R6 known-good) ----------------
// 256 q/block (64/wave, qc=4), 64-key tiles, XOR-swizzled LDS, VGPR-prefetch
// pipeline, PV via K=16 MFMA straight from exp-packed registers (no P LDS).
// XCD-locality swizzle: XCD (bid&7) owns bh in [xcd*8, xcd*8+8) -> K/V (4 MB)
// stays L2-resident across its 8 q-blocks.
// NOTE: __launch_bounds__(256,2) — do NOT tighten; (256,4) caps VGPR at 128 and
// spills the accumulators (R7: 3 GB scratch traffic, 7.8x regression).
__global__ __launch_bounds__(256, 2) void attention_k(const uint16_t* __restrict__ qm,
                                                      const uint16_t* __restrict__ km,
                                                      const uint16_t* __restrict__ vtm,
                                                      uint16_t* __restrict__ om) {
  __shared__ __align__(16) uint16_t Ks[64 * 64];
  __shared__ __align__(16) uint16_t Vs[64 * 64];
  const int tid = threadIdx.x;
  const int wave = tid >> 6, lane = tid & 63;
  const int g = lane >> 4, c16 = lane & 15;

  const int bid = blockIdx.x;
  const int xcd = bid & 7;
  const int l0 = bid >> 3;
  const int bh = xcd * 8 + (l0 & 7);
  const int qblk = l0 >> 3;
  const int b = bh >> 4, h = bh & 15;
  const int q0 = qblk * 256 + wave * 64;

  const uint16_t* qbase = qm + (size_t)bh * N_SEQ * DH;
  const uint16_t* kbase = km + (size_t)bh * N_SEQ * DH;
  const uint16_t* vbase = vtm + (size_t)bh * DH * N_SEQ;

  bf16x8 qf[4][2];
#pragma unroll
  for (int qc = 0; qc < 4; ++qc) {
    const uint16_t* qp = qbase + (size_t)(q0 + qc * 16 + c16) * DH + g * 8;
    qf[qc][0] = *(const bf16x8*)qp;
    qf[qc][1] = *(const bf16x8*)(qp + 32);
  }

  const f32x4 fz = {0.f, 0.f, 0.f, 0.f};
  f32x4 oacc[4][4];
#pragma unroll
  for (int qc = 0; qc < 4; ++qc)
#pragma unroll
    for (int jt = 0; jt < 4; ++jt) oacc[qc][jt] = fz;
  float l[4] = {0.f, 0.f, 0.f, 0.f};

  const int sw = c16 & 7;

  const int ch = tid & 7;
  const int krow0 = tid >> 3, krow1 = (256 + tid) >> 3;
  const int kdst0 = krow0 * 64 + ((ch ^ (krow0 & 7)) << 3);
  const int kdst1 = krow1 * 64 + ((ch ^ (krow1 & 7)) << 3);

  uint4 kp0, kp1, vp0, vp1;
  kp0 = *(const uint4*)&kbase[(size_t)tid * 8];
  kp1 = *(const uint4*)&kbase[(size_t)(256 + tid) * 8];
  vp0 = *(const uint4*)&vbase[(size_t)krow0 * N_SEQ + ch * 8];
  vp1 = *(const uint4*)&vbase[(size_t)krow1 * N_SEQ + ch * 8];
  *(uint4*)&Ks[kdst0] = kp0;
  *(uint4*)&Ks[kdst1] = kp1;
  *(uint4*)&Vs[kdst0] = vp0;
  *(uint4*)&Vs[kdst1] = vp1;
  __syncthreads();

  for (int t = 0; t < N_SEQ / 64; ++t) {
    if (t < N_SEQ / 64 - 1) {
      const size_t ko = (size_t)(t + 1) * 4096;
      const int vc = (t + 1) * 64;
      kp0 = *(const uint4*)&kbase[ko + (size_t)tid * 8];
      kp1 = *(const uint4*)&kbase[ko + (size_t)(256 + tid) * 8];
      vp0 = *(const uint4*)&vbase[(size_t)krow0 * N_SEQ + vc + ch * 8];
      vp1 = *(const uint4*)&vbase[(size_t)krow1 * N_SEQ + vc + ch * 8];
    }

#pragma unroll
    for (int kt = 0; kt < 4; ++kt) {
      const int krow = kt * 16 + c16;
      bf16x8 kf0 = *(const bf16x8*)&Ks[krow * 64 + ((g ^ sw) << 3)];
      bf16x8 kf1 = *(const bf16x8*)&Ks[krow * 64 + (((4 + g) ^ sw) << 3)];
      bf16x4 pk[4];
#pragma unroll
      for (int qc = 0; qc < 4; ++qc) {
        f32x4 z = fz;
        z = __builtin_amdgcn_mfma_f32_16x16x32_bf16(kf0, qf[qc][0], z, 0, 0, 0);
        z = __builtin_amdgcn_mfma_f32_16x16x32_bf16(kf1, qf[qc][1], z, 0, 0, 0);
        f32x4 pv;
        pv[0] = __builtin_amdgcn_exp2f(z[0]);
        pv[1] = __builtin_amdgcn_exp2f(z[1]);
        pv[2] = __builtin_amdgcn_exp2f(z[2]);
        pv[3] = __builtin_amdgcn_exp2f(z[3]);
        l[qc] += (pv[0] + pv[1]) + (pv[2] + pv[3]);
        pk[qc] = __builtin_convertvector(pv, bf16x4);
      }
#pragma unroll
      for (int jt = 0; jt < 4; ++jt) {
        bf16x4 vb = *(const bf16x4*)&Vs[(jt * 16 + c16) * 64 +
                                        (((kt * 2 + (g >> 1)) ^ sw) << 3) + (g & 1) * 4];
#pragma unroll
        for (int qc = 0; qc < 4; ++qc) oacc[qc][jt] = mfma16(pk[qc], vb, oacc[qc][jt]);
      }
    }

    if (t < N_SEQ / 64 - 1) {
      __syncthreads();
      *(uint4*)&Ks[kdst0] = kp0;
      *(uint4*)&Ks[kdst1] = kp1;
      *(uint4*)&Vs[kdst0] = vp0;
      *(uint4*)&Vs[kdst1] = vp1;
      __syncthreads();
    }
  }

#pragma unroll
  for (int qc = 0; qc < 4; ++qc) {
    l[qc] += __shfl_xor(l[qc], 16);
    l[qc] += __shfl_xor(l[qc], 32);
  }

#pragma unroll
  for (int qc = 0; qc < 4; ++qc) {
#pragma unroll
    for (int r = 0; r < 4; ++r) {
      const float lr = __shfl(l[qc], g * 4 + r, 16);
      const float inv = 1.f / lr;
      const int row = q0 + qc * 16 + g * 4 + r;
      const size_t base = ((size_t)b * N_SEQ + row) * 1024 + h * 64;
#pragma unroll
      for (int jt = 0; jt < 4; ++jt)
        om[base + jt * 16 + c16] = f2bf(oacc[qc][jt][r] * inv);
    }
  }
}

// ---------------- LayerNorm + residual ----------------
__global__ __launch_bounds__(256) void ln_res_k(const float* __restrict__ proj,
                                                const float* __restrict__ query,
                                                const float* __restrict__ gamma,
                                                const float* __restrict__ beta,
                                                float* __restrict__ out) {
  const int row = blockIdx.x;
  const int tid = threadIdx.x;
  const size_t base = (size_t)row * 1024 + tid * 4;
  float4 v = *(const float4*)(proj + base);
  float s = v.x + v.y + v.z + v.w;
  float s2 = v.x * v.x + v.y * v.y + v.z * v.z + v.w * v.w;
#pragma unroll
  for (int off = 1; off < 64; off <<= 1) {
    s += __shfl_xor(s, off);
    s2 += __shfl_xor(s2, off);
  }
  __shared__ float red[8];
  const int wave = tid >> 6, lane = tid & 63;
  if (lane == 0) { red[wave] = s; red[4 + wave] = s2; }
  __syncthreads();
  s = red[0] + red[1] + red[2] + red[3];
  s2 = red[4] + red[5] + red[6] + red[7];
  const float mu = s * (1.f / 1024.f);
  const float var = fmaxf(s2 * (1.f / 1024.f) - mu * mu, 0.f);
  const float rstd = rsqrtf(var + 1e-5f);
  float4 gq = *(const float4*)(gamma + tid * 4);
  float4 bq = *(const float4*)(beta + tid * 4);
  float4 qq = *(const float4*)(query + base);
  float4 o;
  o.x = (v.x - mu) * rstd * gq.x + bq.x + qq.x;
  o.y = (v.y - mu) * rstd * gq.y + bq.y + qq.y;
  o.z = (v.z - mu) * rstd * gq.z + bq.z + qq.z;
  o.w = (v.w - mu) * rstd * gq.w + bq.w + qq.w;
  *(float4*)(out + base) = o;
}

extern "C" void kernel_launch(void* const* d_in, const int* in_sizes, int n_in,
                              void* d_out, int out_size, void* d_ws, size_t ws_size,
                              hipStream_t stream) {
  (void)in_sizes; (void)n_in; (void)out_size; (void)ws_size;
  const float* query = (const float*)d_in[0];
  const float* key_ = (const float*)d_in[1];
  const float* value = (const float*)d_in[2];
  const float* Wq = (const float*)d_in[3];
  const float* Wk = (const float*)d_in[4];
  const float* Wv = (const float*)d_in[5];
  const float* Wo = (const float*)d_in[6];
  const float* bo = (const float*)d_in[7];
  const float* gamma = (const float*)d_in[8];
  const float* beta = (const float*)d_in[9];
  float* out = (float*)d_out;

  const size_t NELEM = (size_t)M_TOT * 1024;  // 8388608
  uint16_t* wsp = (uint16_t*)d_ws;
  uint16_t* WqT = wsp;                    // 4 x 1M bf16 (Wq,Wk,Wv,Wo contiguous)
  uint16_t* WoT = WqT + 3 * 1024 * 1024;
  uint16_t* qb = wsp + 4 * 1024 * 1024;   // qb,kb,vt contiguous (z * NELEM)
  uint16_t* attnO = qb + 3 * NELEM;       // bf16 [B,N,1024]
  float* proj = (float*)(attnO + NELEM);  // fp32 [M,1024]

  transpose_conv<<<dim3(32, 32, 4), dim3(32, 8), 0, stream>>>(Wq, Wk, Wv, Wo, WqT);

  gemm_qkv<<<1536, 256, 0, stream>>>(query, key_, value, WqT, qb);

  attention_k<<<512, 256, 0, stream>>>(qb, qb + NELEM, qb + 2 * NELEM, attnO);

  gemm_out<<<512, 256, 0, stream>>>(attnO, WoT, proj, bo);

  ln_res_k<<<8192, 256, 0, stream>>>(proj, query, gamma, beta, out);
}

// Round 9
// 356.223 us; speedup vs baseline: 2.6275x; 1.0314x over previous
//
#include <hip/hip_runtime.h>
#include <stdint.h>

#define K_DIM 1024
#define B_SZ 4
#define N_SEQ 2048
#define HEADS 16
#define DH 64
#define M_TOT (B_SZ * N_SEQ)  // 8192

typedef __bf16 bf16x8 __attribute__((ext_vector_type(8)));
typedef __bf16 bf16x4 __attribute__((ext_vector_type(4)));
typedef float f32x4 __attribute__((ext_vector_type(4)));
typedef float f32x8 __attribute__((ext_vector_type(8)));
typedef short s16x4 __attribute__((ext_vector_type(4)));

typedef const uint32_t __attribute__((address_space(1))) gas_u32;
typedef uint32_t __attribute__((address_space(3))) las_u32;

#define CE_SCALE 0.1803368801f  // 0.125 * log2(e), folded into Q projection

__device__ __forceinline__ uint16_t f2bf(float f) {
  uint32_t u = __float_as_uint(f);
  u += 0x7FFFu + ((u >> 16) & 1u);  // round-nearest-even
  return (uint16_t)(u >> 16);
}

__device__ __forceinline__ void gld_lds16(const void* g, void* lds) {
  __builtin_amdgcn_global_load_lds((gas_u32*)g, (las_u32*)lds, 16, 0, 0);
}

// K=16 bf16 MFMA: A-operand layout (k = quad*4 + j) == our S^T C-layout.
#if defined(__has_builtin)
#if __has_builtin(__builtin_amdgcn_mfma_f32_16x16x16bf16_1k)
#define HAVE_MFMA16_BUILTIN 1
#endif
#endif

__device__ __forceinline__ f32x4 mfma16(bf16x4 a, bf16x4 b, f32x4 c) {
#ifdef HAVE_MFMA16_BUILTIN
  return __builtin_amdgcn_mfma_f32_16x16x16bf16_1k(
      __builtin_bit_cast(s16x4, a), __builtin_bit_cast(s16x4, b), c, 0, 0, 0);
#else
  f32x4 d;
  asm("v_mfma_f32_16x16x16_bf16 %0, %1, %2, %3"
      : "=v"(d)
      : "v"(a), "v"(b), "v"(c));
  return d;
#endif
}

// ------------- transpose + convert weights (batched over 4) ----------------------
__global__ __launch_bounds__(256) void transpose_conv(const float* __restrict__ s0,
                                                      const float* __restrict__ s1,
                                                      const float* __restrict__ s2,
                                                      const float* __restrict__ s3,
                                                      uint16_t* __restrict__ dstbase) {
  __shared__ float tile[32][33];
  const int z = blockIdx.z;
  const float* src = (z == 0) ? s0 : (z == 1) ? s1 : (z == 2) ? s2 : s3;
  uint16_t* dst = dstbase + (size_t)z * 1024 * 1024;
  const int tx = threadIdx.x, ty = threadIdx.y;
  const int bx = blockIdx.x * 32, by = blockIdx.y * 32;
#pragma unroll
  for (int i = 0; i < 32; i += 8)
    tile[ty + i][tx] = src[(size_t)(by + ty + i) * 1024 + bx + tx];
  __syncthreads();
#pragma unroll
  for (int i = 0; i < 32; i += 8)
    dst[(size_t)(bx + ty + i) * 1024 + by + tx] = f2bf(tile[tx][ty + i]);
}

// ---------------- fused QKV GEMM, fp32 A staged via global_load_lds --------------
// C_z[M,1024] = cvt_bf16(A_z) @ B_z; A_z = {query,key_,value} fp32 read DIRECTLY.
// A tile staged in LDS as fp32 (global_load_lds, 16B=4 floats/lane, source-XOR
// swizzle chunk^row&7 so fragment reads are <=2-way); convert to bf16 at
// fragment-read time (2x ds_read_b128 + v_cvt_pk per fragment). K-loop barrier
// structure is IDENTICAL to the proven R6 all-gld_lds one (R8's VGPR round-trip
// staging was latency-bound: 127us with all pipes <16% busy).
// XCD swizzle: XCD (bid&7) owns m-tiles [xcd*8, xcd*8+8); n fastest, z slowest.
// z=0: Q scaled by CE -> [B,H,N,Dh]; z=1: K -> [B,H,N,Dh]; z=2: V -> [B,H,Dh,N].
__global__ __launch_bounds__(256, 2) void gemm_qkv(const float* __restrict__ Aq,
                                                   const float* __restrict__ Ak,
                                                   const float* __restrict__ Av,
                                                   const uint16_t* __restrict__ BT,
                                                   uint16_t* __restrict__ Cout) {
  __shared__ __align__(16) float Asf[128 * 32];    // 16 KB fp32 A tile
  __shared__ __align__(16) uint16_t Bs[128 * 32];  // 8 KB bf16 B tile
  const int tid = threadIdx.x;
  const int wave = tid >> 6, lane = tid & 63;
  const int g = lane >> 4, c16 = lane & 15;

  const int bid = blockIdx.x;
  const int xcd = bid & 7;
  const int l = bid >> 3;
  const int z = l >> 6;
  const int r = l & 63;
  const int n0 = (r & 7) * 128;
  const int m0 = (xcd * 8 + (r >> 3)) * 128;

  const int wr = wave >> 1, wc = wave & 1;
  const float* A = (z == 0) ? Aq : (z == 1) ? Ak : Av;
  const uint16_t* Bz = BT + (size_t)z * 1024 * 1024;
  const float scale = (z == 0) ? CE_SCALE : 1.f;

  const f32x4 fzero = {0.f, 0.f, 0.f, 0.f};
  f32x4 acc[4][4];
#pragma unroll
  for (int i = 0; i < 4; ++i)
#pragma unroll
    for (int j = 0; j < 4; ++j) acc[i][j] = fzero;

  // A staging: lane covers row_local = lane>>3 (8 rows/call), chunk = lane&7;
  // source chunk XOR-swizzled by row&7 (dest stays linear for gld_lds).
  const int arl = lane >> 3, ach = lane & 7;
  const int asc = ((ach ^ (arl & 7)) << 2);  // float offset within 32-float row
  const float* agp[4];
  float* adp[4];
#pragma unroll
  for (int q = 0; q < 4; ++q) {
    agp[q] = A + (size_t)(m0 + wave * 32 + q * 8 + arl) * K_DIM + asc;
    adp[q] = Asf + (wave * 32 + q * 8) * 32;
  }

  // B staging (bf16, 16 rows per gld_lds call)
  const int srow = wave * 32 + (lane >> 2);
  const int scol = (lane & 3) * 8;
  const uint16_t* bg0 = Bz + (size_t)(n0 + srow) * K_DIM + scol;
  const uint16_t* bg1 = Bz + (size_t)(n0 + srow + 16) * K_DIM + scol;
  uint16_t* lb0 = &Bs[(wave * 32) * 32];
  uint16_t* lb1 = &Bs[(wave * 32 + 16) * 32];

  for (int kt = 0; kt < K_DIM / 32; ++kt) {
    __syncthreads();
#pragma unroll
    for (int q = 0; q < 4; ++q) gld_lds16(agp[q] + kt * 32, adp[q]);
    gld_lds16(bg0 + kt * 32, lb0);
    gld_lds16(bg1 + kt * 32, lb1);
    __syncthreads();  // drains all gld_lds -> tiles visible

    bf16x8 avec[4], bvec[4];
#pragma unroll
    for (int i = 0; i < 4; ++i) {
      const int rA = wr * 64 + i * 16 + c16;
      const int rb = rA & 7;
      f32x4 a0 = *(const f32x4*)&Asf[rA * 32 + (((2 * g) ^ rb) << 2)];
      f32x4 a1 = *(const f32x4*)&Asf[rA * 32 + (((2 * g + 1) ^ rb) << 2)];
      f32x8 af = __builtin_shufflevector(a0, a1, 0, 1, 2, 3, 4, 5, 6, 7);
      avec[i] = __builtin_convertvector(af, bf16x8);
    }
#pragma unroll
    for (int j = 0; j < 4; ++j)
      bvec[j] = *(const bf16x8*)&Bs[(wc * 64 + j * 16 + c16) * 32 + g * 8];
#pragma unroll
    for (int i = 0; i < 4; ++i)
#pragma unroll
      for (int j = 0; j < 4; ++j)
        acc[i][j] = __builtin_amdgcn_mfma_f32_16x16x32_bf16(avec[i], bvec[j], acc[i][j], 0, 0, 0);
  }

#pragma unroll
  for (int i = 0; i < 4; ++i) {
#pragma unroll
    for (int j = 0; j < 4; ++j) {
      const int col = n0 + wc * 64 + j * 16 + c16;
      if (z == 2) {
        // V^T layout [b*16+h][d][n]; rows g*4+r2 are 4 consecutive n -> 8B store
        const int h = col >> 6, d = col & 63;
        const int row0 = m0 + wr * 64 + i * 16 + g * 4;
        const int b = row0 >> 11, n = row0 & 2047;
        ushort4 o;
        o.x = f2bf(acc[i][j][0]); o.y = f2bf(acc[i][j][1]);
        o.z = f2bf(acc[i][j][2]); o.w = f2bf(acc[i][j][3]);
        *(ushort4*)&Cout[(size_t)2 * M_TOT * 1024 +
                         (((size_t)(b * HEADS + h)) * DH + d) * N_SEQ + n] = o;
      } else {
#pragma unroll
        for (int r2 = 0; r2 < 4; ++r2) {
          const int row = m0 + wr * 64 + i * 16 + g * 4 + r2;
          const int b = row >> 11, n = row & 2047;
          const int h = col >> 6, d = col & 63;
          Cout[(size_t)z * M_TOT * 1024 + (((size_t)(b * HEADS + h)) * N_SEQ + n) * DH + d] =
              f2bf(acc[i][j][r2] * scale);
        }
      }
    }
  }
}

// ---------------- output projection GEMM (bf16 A via global_load_lds) -----------
__global__ __launch_bounds__(256, 2) void gemm_out(const uint16_t* __restrict__ A,
                                                   const uint16_t* __restrict__ BT,
                                                   float* __restrict__ Cout,
                                                   const float* __restrict__ bias) {
  __shared__ __align__(16) uint16_t As[128 * 32];
  __shared__ __align__(16) uint16_t Bs[128 * 32];
  const int tid = threadIdx.x;
  const int wave = tid >> 6, lane = tid & 63;
  const int g = lane >> 4, c16 = lane & 15;

  const int bid = blockIdx.x;
  const int xcd = bid & 7;
  const int l = bid >> 3;
  const int n0 = (l & 7) * 128;
  const int m0 = (xcd * 8 + (l >> 3)) * 128;
  const int wr = wave >> 1, wc = wave & 1;

  const f32x4 fzero = {0.f, 0.f, 0.f, 0.f};
  f32x4 acc[4][4];
#pragma unroll
  for (int i = 0; i < 4; ++i)
#pragma unroll
    for (int j = 0; j < 4; ++j) acc[i][j] = fzero;

  const int srow = wave * 32 + (lane >> 2);
  const int scol = (lane & 3) * 8;
  const uint16_t* ag0 = A + (size_t)(m0 + srow) * K_DIM + scol;
  const uint16_t* ag1 = A + (size_t)(m0 + srow + 16) * K_DIM + scol;
  const uint16_t* bg0 = BT + (size_t)(n0 + srow) * K_DIM + scol;
  const uint16_t* bg1 = BT + (size_t)(n0 + srow + 16) * K_DIM + scol;
  uint16_t* la0 = &As[(wave * 32) * 32];
  uint16_t* la1 = &As[(wave * 32 + 16) * 32];
  uint16_t* lb0 = &Bs[(wave * 32) * 32];
  uint16_t* lb1 = &Bs[(wave * 32 + 16) * 32];

  for (int kt = 0; kt < K_DIM / 32; ++kt) {
    __syncthreads();
    gld_lds16(ag0 + kt * 32, la0);
    gld_lds16(ag1 + kt * 32, la1);
    gld_lds16(bg0 + kt * 32, lb0);
    gld_lds16(bg1 + kt * 32, lb1);
    __syncthreads();
    bf16x8 avec[4], bvec[4];
#pragma unroll
    for (int i = 0; i < 4; ++i)
      avec[i] = *(const bf16x8*)&As[(wr * 64 + i * 16 + c16) * 32 + g * 8];
#pragma unroll
    for (int j = 0; j < 4; ++j)
      bvec[j] = *(const bf16x8*)&Bs[(wc * 64 + j * 16 + c16) * 32 + g * 8];
#pragma unroll
    for (int i = 0; i < 4; ++i)
#pragma unroll
      for (int j = 0; j < 4; ++j)
        acc[i][j] = __builtin_amdgcn_mfma_f32_16x16x32_bf16(avec[i], bvec[j], acc[i][j], 0, 0, 0);
  }

#pragma unroll
  for (int i = 0; i < 4; ++i) {
#pragma unroll
    for (int j = 0; j < 4; ++j) {
      const int col = n0 + wc * 64 + j * 16 + c16;
#pragma unroll
      for (int r2 = 0; r2 < 4; ++r2) {
        const int row = m0 + wr * 64 + i * 16 + g * 4 + r2;
        Cout[(size_t)row * 1024 + col] = acc[i][j][r2] + bias[col];
      }
    }
  }
}

// ---------------- flash attention (R6 known-good) ----------------
// NOTE: __launch_bounds__(256,2) — do NOT tighten; (256,4) caps VGPR at 128 and
// spills the accumulators (R7: 3 GB scratch traffic, 7.8x regression).
__global__ __launch_bounds__(256, 2) void attention_k(const uint16_t* __restrict__ qm,
                                                      const uint16_t* __restrict__ km,
                                                      const uint16_t* __restrict__ vtm,
                                                      uint16_t* __restrict__ om) {
  __shared__ __align__(16) uint16_t Ks[64 * 64];
  __shared__ __align__(16) uint16_t Vs[64 * 64];
  const int tid = threadIdx.x;
  const int wave = tid >> 6, lane = tid & 63;
  const int g = lane >> 4, c16 = lane & 15;

  const int bid = blockIdx.x;
  const int xcd = bid & 7;
  const int l0 = bid >> 3;
  const int bh = xcd * 8 + (l0 & 7);
  const int qblk = l0 >> 3;
  const int b = bh >> 4, h = bh & 15;
  const int q0 = qblk * 256 + wave * 64;

  const uint16_t* qbase = qm + (size_t)bh * N_SEQ * DH;
  const uint16_t* kbase = km + (size_t)bh * N_SEQ * DH;
  const uint16_t* vbase = vtm + (size_t)bh * DH * N_SEQ;

  bf16x8 qf[4][2];
#pragma unroll
  for (int qc = 0; qc < 4; ++qc) {
    const uint16_t* qp = qbase + (size_t)(q0 + qc * 16 + c16) * DH + g * 8;
    qf[qc][0] = *(const bf16x8*)qp;
    qf[qc][1] = *(const bf16x8*)(qp + 32);
  }

  const f32x4 fz = {0.f, 0.f, 0.f, 0.f};
  f32x4 oacc[4][4];
#pragma unroll
  for (int qc = 0; qc < 4; ++qc)
#pragma unroll
    for (int jt = 0; jt < 4; ++jt) oacc[qc][jt] = fz;
  float l[4] = {0.f, 0.f, 0.f, 0.f};

  const int sw = c16 & 7;

  const int ch = tid & 7;
  const int krow0 = tid >> 3, krow1 = (256 + tid) >> 3;
  const int kdst0 = krow0 * 64 + ((ch ^ (krow0 & 7)) << 3);
  const int kdst1 = krow1 * 64 + ((ch ^ (krow1 & 7)) << 3);

  uint4 kp0, kp1, vp0, vp1;
  kp0 = *(const uint4*)&kbase[(size_t)tid * 8];
  kp1 = *(const uint4*)&kbase[(size_t)(256 + tid) * 8];
  vp0 = *(const uint4*)&vbase[(size_t)krow0 * N_SEQ + ch * 8];
  vp1 = *(const uint4*)&vbase[(size_t)krow1 * N_SEQ + ch * 8];
  *(uint4*)&Ks[kdst0] = kp0;
  *(uint4*)&Ks[kdst1] = kp1;
  *(uint4*)&Vs[kdst0] = vp0;
  *(uint4*)&Vs[kdst1] = vp1;
  __syncthreads();

  for (int t = 0; t < N_SEQ / 64; ++t) {
    if (t < N_SEQ / 64 - 1) {
      const size_t ko = (size_t)(t + 1) * 4096;
      const int vc = (t + 1) * 64;
      kp0 = *(const uint4*)&kbase[ko + (size_t)tid * 8];
      kp1 = *(const uint4*)&kbase[ko + (size_t)(256 + tid) * 8];
      vp0 = *(const uint4*)&vbase[(size_t)krow0 * N_SEQ + vc + ch * 8];
      vp1 = *(const uint4*)&vbase[(size_t)krow1 * N_SEQ + vc + ch * 8];
    }

#pragma unroll
    for (int kt = 0; kt < 4; ++kt) {
      const int krow = kt * 16 + c16;
      bf16x8 kf0 = *(const bf16x8*)&Ks[krow * 64 + ((g ^ sw) << 3)];
      bf16x8 kf1 = *(const bf16x8*)&Ks[krow * 64 + (((4 + g) ^ sw) << 3)];
      bf16x4 pk[4];
#pragma unroll
      for (int qc = 0; qc < 4; ++qc) {
        f32x4 z = fz;
        z = __builtin_amdgcn_mfma_f32_16x16x32_bf16(kf0, qf[qc][0], z, 0, 0, 0);
        z = __builtin_amdgcn_mfma_f32_16x16x32_bf16(kf1, qf[qc][1], z, 0, 0, 0);
        f32x4 pv;
        pv[0] = __builtin_amdgcn_exp2f(z[0]);
        pv[1] = __builtin_amdgcn_exp2f(z[1]);
        pv[2] = __builtin_amdgcn_exp2f(z[2]);
        pv[3] = __builtin_amdgcn_exp2f(z[3]);
        l[qc] += (pv[0] + pv[1]) + (pv[2] + pv[3]);
        pk[qc] = __builtin_convertvector(pv, bf16x4);
      }
#pragma unroll
      for (int jt = 0; jt < 4; ++jt) {
        bf16x4 vb = *(const bf16x4*)&Vs[(jt * 16 + c16) * 64 +
                                        (((kt * 2 + (g >> 1)) ^ sw) << 3) + (g & 1) * 4];
#pragma unroll
        for (int qc = 0; qc < 4; ++qc) oacc[qc][jt] = mfma16(pk[qc], vb, oacc[qc][jt]);
      }
    }

    if (t < N_SEQ / 64 - 1) {
      __syncthreads();
      *(uint4*)&Ks[kdst0] = kp0;
      *(uint4*)&Ks[kdst1] = kp1;
      *(uint4*)&Vs[kdst0] = vp0;
      *(uint4*)&Vs[kdst1] = vp1;
      __syncthreads();
    }
  }

#pragma unroll
  for (int qc = 0; qc < 4; ++qc) {
    l[qc] += __shfl_xor(l[qc], 16);
    l[qc] += __shfl_xor(l[qc], 32);
  }

#pragma unroll
  for (int qc = 0; qc < 4; ++qc) {
#pragma unroll
    for (int r = 0; r < 4; ++r) {
      const float lr = __shfl(l[qc], g * 4 + r, 16);
      const float inv = 1.f / lr;
      const int row = q0 + qc * 16 + g * 4 + r;
      const size_t base = ((size_t)b * N_SEQ + row) * 1024 + h * 64;
#pragma unroll
      for (int jt = 0; jt < 4; ++jt)
        om[base + jt * 16 + c16] = f2bf(oacc[qc][jt][r] * inv);
    }
  }
}

// ---------------- LayerNorm + residual ----------------
__global__ __launch_bounds__(256) void ln_res_k(const float* __restrict__ proj,
                                                const float* __restrict__ query,
                                                const float* __restrict__ gamma,
                                                const float* __restrict__ beta,
                                                float* __restrict__ out) {
  const int row = blockIdx.x;
  const int tid = threadIdx.x;
  const size_t base = (size_t)row * 1024 + tid * 4;
  float4 v = *(const float4*)(proj + base);
  float s = v.x + v.y + v.z + v.w;
  float s2 = v.x * v.x + v.y * v.y + v.z * v.z + v.w * v.w;
#pragma unroll
  for (int off = 1; off < 64; off <<= 1) {
    s += __shfl_xor(s, off);
    s2 += __shfl_xor(s2, off);
  }
  __shared__ float red[8];
  const int wave = tid >> 6, lane = tid & 63;
  if (lane == 0) { red[wave] = s; red[4 + wave] = s2; }
  __syncthreads();
  s = red[0] + red[1] + red[2] + red[3];
  s2 = red[4] + red[5] + red[6] + red[7];
  const float mu = s * (1.f / 1024.f);
  const float var = fmaxf(s2 * (1.f / 1024.f) - mu * mu, 0.f);
  const float rstd = rsqrtf(var + 1e-5f);
  float4 gq = *(const float4*)(gamma + tid * 4);
  float4 bq = *(const float4*)(beta + tid * 4);
  float4 qq = *(const float4*)(query + base);
  float4 o;
  o.x = (v.x - mu) * rstd * gq.x + bq.x + qq.x;
  o.y = (v.y - mu) * rstd * gq.y + bq.y + qq.y;
  o.z = (v.z - mu) * rstd * gq.z + bq.z + qq.z;
  o.w = (v.w - mu) * rstd * gq.w + bq.w + qq.w;
  *(float4*)(out + base) = o;
}

extern "C" void kernel_launch(void* const* d_in, const int* in_sizes, int n_in,
                              void* d_out, int out_size, void* d_ws, size_t ws_size,
                              hipStream_t stream) {
  (void)in_sizes; (void)n_in; (void)out_size; (void)ws_size;
  const float* query = (const float*)d_in[0];
  const float* key_ = (const float*)d_in[1];
  const float* value = (const float*)d_in[2];
  const float* Wq = (const float*)d_in[3];
  const float* Wk = (const float*)d_in[4];
  const float* Wv = (const float*)d_in[5];
  const float* Wo = (const float*)d_in[6];
  const float* bo = (const float*)d_in[7];
  const float* gamma = (const float*)d_in[8];
  const float* beta = (const float*)d_in[9];
  float* out = (float*)d_out;

  const size_t NELEM = (size_t)M_TOT * 1024;  // 8388608
  uint16_t* wsp = (uint16_t*)d_ws;
  uint16_t* WqT = wsp;                    // 4 x 1M bf16 (Wq,Wk,Wv,Wo contiguous)
  uint16_t* WoT = WqT + 3 * 1024 * 1024;
  uint16_t* qb = wsp + 4 * 1024 * 1024;   // qb,kb,vt contiguous (z * NELEM)
  uint16_t* attnO = qb + 3 * NELEM;       // bf16 [B,N,1024]
  float* proj = (float*)(attnO + NELEM);  // fp32 [M,1024]

  transpose_conv<<<dim3(32, 32, 4), dim3(32, 8), 0, stream>>>(Wq, Wk, Wv, Wo, WqT);

  gemm_qkv<<<1536, 256, 0, stream>>>(query, key_, value, WqT, qb);

  attention_k<<<512, 256, 0, stream>>>(qb, qb + NELEM, qb + 2 * NELEM, attnO);

  gemm_out<<<512, 256, 0, stream>>>(attnO, WoT, proj, bo);

  ln_res_k<<<8192, 256, 0, stream>>>(proj, query, gamma, beta, out);
}

// Round 10
// 353.850 us; speedup vs baseline: 2.6451x; 1.0067x over previous
//
#include <hip/hip_runtime.h>
#include <stdint.h>

#define K_DIM 1024
#define B_SZ 4
#define N_SEQ 2048
#define HEADS 16
#define DH 64
#define M_TOT (B_SZ * N_SEQ)  // 8192

typedef __bf16 bf16x8 __attribute__((ext_vector_type(8)));
typedef __bf16 bf16x4 __attribute__((ext_vector_type(4)));
typedef float f32x4 __attribute__((ext_vector_type(4)));
typedef float f32x8 __attribute__((ext_vector_type(8)));
typedef short s16x4 __attribute__((ext_vector_type(4)));

typedef const uint32_t __attribute__((address_space(1))) gas_u32;
typedef uint32_t __attribute__((address_space(3))) las_u32;

#define CE_SCALE 0.1803368801f  // 0.125 * log2(e), folded into Q projection

__device__ __forceinline__ uint16_t f2bf(float f) {
  uint32_t u = __float_as_uint(f);
  u += 0x7FFFu + ((u >> 16) & 1u);  // round-nearest-even
  return (uint16_t)(u >> 16);
}

__device__ __forceinline__ void gld_lds16(const void* g, void* lds) {
  __builtin_amdgcn_global_load_lds((gas_u32*)g, (las_u32*)lds, 16, 0, 0);
}

// K=16 bf16 MFMA: A-operand layout (k = quad*4 + j) == our S^T C-layout.
#if defined(__has_builtin)
#if __has_builtin(__builtin_amdgcn_mfma_f32_16x16x16bf16_1k)
#define HAVE_MFMA16_BUILTIN 1
#endif
#endif

__device__ __forceinline__ f32x4 mfma16(bf16x4 a, bf16x4 b, f32x4 c) {
#ifdef HAVE_MFMA16_BUILTIN
  return __builtin_amdgcn_mfma_f32_16x16x16bf16_1k(
      __builtin_bit_cast(s16x4, a), __builtin_bit_cast(s16x4, b), c, 0, 0, 0);
#else
  f32x4 d;
  asm("v_mfma_f32_16x16x16_bf16 %0, %1, %2, %3"
      : "=v"(d)
      : "v"(a), "v"(b), "v"(c));
  return d;
#endif
}

// ------------- transpose + convert weights (batched over 4) ----------------------
__global__ __launch_bounds__(256) void transpose_conv(const float* __restrict__ s0,
                                                      const float* __restrict__ s1,
                                                      const float* __restrict__ s2,
                                                      const float* __restrict__ s3,
                                                      uint16_t* __restrict__ dstbase) {
  __shared__ float tile[32][33];
  const int z = blockIdx.z;
  const float* src = (z == 0) ? s0 : (z == 1) ? s1 : (z == 2) ? s2 : s3;
  uint16_t* dst = dstbase + (size_t)z * 1024 * 1024;
  const int tx = threadIdx.x, ty = threadIdx.y;
  const int bx = blockIdx.x * 32, by = blockIdx.y * 32;
#pragma unroll
  for (int i = 0; i < 32; i += 8)
    tile[ty + i][tx] = src[(size_t)(by + ty + i) * 1024 + bx + tx];
  __syncthreads();
#pragma unroll
  for (int i = 0; i < 32; i += 8)
    dst[(size_t)(bx + ty + i) * 1024 + by + tx] = f2bf(tile[tx][ty + i]);
}

// ---------------- fused QKV GEMM, double-buffered single-barrier K-loop ----------
// C_z[M,1024] = cvt_bf16(A_z) @ B_z; A_z = {query,key_,value} fp32 read DIRECTLY.
// Pipeline: barrier at iter kt drains loads issued at kt-1 (they had the whole
// previous MFMA stretch to land) -> issue tile kt+1 into the other buffer ->
// compute tile kt. ONE barrier/iter; staging latency hidden by construction.
// (R9's two-barrier loop exposed the full vmcnt drain every iter: 122us, all
// pipes <17% busy.)
// A staged fp32 w/ source-XOR swizzle (chunk^row&7); cvt at fragment-read time.
// XCD swizzle: XCD (bid&7) owns m-tiles [xcd*8, xcd*8+8); n fastest, z slowest.
// z=0: Q scaled by CE -> [B,H,N,Dh]; z=1: K -> [B,H,N,Dh]; z=2: V -> [B,H,Dh,N].
__global__ __launch_bounds__(256, 2) void gemm_qkv(const float* __restrict__ Aq,
                                                   const float* __restrict__ Ak,
                                                   const float* __restrict__ Av,
                                                   const uint16_t* __restrict__ BT,
                                                   uint16_t* __restrict__ Cout) {
  __shared__ __align__(16) float As0[128 * 32];    // 16 KB
  __shared__ __align__(16) float As1[128 * 32];    // 16 KB
  __shared__ __align__(16) uint16_t Bs0[128 * 32]; // 8 KB
  __shared__ __align__(16) uint16_t Bs1[128 * 32]; // 8 KB
  const int tid = threadIdx.x;
  const int wave = tid >> 6, lane = tid & 63;
  const int g = lane >> 4, c16 = lane & 15;

  const int bid = blockIdx.x;
  const int xcd = bid & 7;
  const int l = bid >> 3;
  const int z = l >> 6;
  const int r = l & 63;
  const int n0 = (r & 7) * 128;
  const int m0 = (xcd * 8 + (r >> 3)) * 128;

  const int wr = wave >> 1, wc = wave & 1;
  const float* A = (z == 0) ? Aq : (z == 1) ? Ak : Av;
  const uint16_t* Bz = BT + (size_t)z * 1024 * 1024;
  const float scale = (z == 0) ? CE_SCALE : 1.f;

  const f32x4 fzero = {0.f, 0.f, 0.f, 0.f};
  f32x4 acc[4][4];
#pragma unroll
  for (int i = 0; i < 4; ++i)
#pragma unroll
    for (int j = 0; j < 4; ++j) acc[i][j] = fzero;

  // A staging: lane covers row_local = lane>>3 (8 rows/call), chunk = lane&7;
  // source chunk XOR-swizzled by row&7 (dest stays linear for gld_lds).
  const int arl = lane >> 3, ach = lane & 7;
  const int asc = ((ach ^ (arl & 7)) << 2);
  const float* agp[4];
  int adpo[4];
#pragma unroll
  for (int q = 0; q < 4; ++q) {
    agp[q] = A + (size_t)(m0 + wave * 32 + q * 8 + arl) * K_DIM + asc;
    adpo[q] = (wave * 32 + q * 8) * 32;
  }

  // B staging (bf16, 16 rows per gld_lds call)
  const int srow = wave * 32 + (lane >> 2);
  const int scol = (lane & 3) * 8;
  const uint16_t* bg0 = Bz + (size_t)(n0 + srow) * K_DIM + scol;
  const uint16_t* bg1 = Bz + (size_t)(n0 + srow + 16) * K_DIM + scol;
  const int lbo0 = (wave * 32) * 32;
  const int lbo1 = (wave * 32 + 16) * 32;

  // prologue: tile 0 -> buffer 0
#pragma unroll
  for (int q = 0; q < 4; ++q) gld_lds16(agp[q], As0 + adpo[q]);
  gld_lds16(bg0, Bs0 + lbo0);
  gld_lds16(bg1, Bs0 + lbo1);

  float* a_cur = As0;
  float* a_nxt = As1;
  uint16_t* b_cur = Bs0;
  uint16_t* b_nxt = Bs1;

  for (int kt = 0; kt < K_DIM / 32; ++kt) {
    __syncthreads();  // drains tile-kt loads (issued last iter); syncs readers of a_nxt
    if (kt + 1 < K_DIM / 32) {
      const int ko = (kt + 1) * 32;
#pragma unroll
      for (int q = 0; q < 4; ++q) gld_lds16(agp[q] + ko, a_nxt + adpo[q]);
      gld_lds16(bg0 + ko, b_nxt + lbo0);
      gld_lds16(bg1 + ko, b_nxt + lbo1);
    }

    bf16x8 avec[4], bvec[4];
#pragma unroll
    for (int i = 0; i < 4; ++i) {
      const int rA = wr * 64 + i * 16 + c16;
      const int rb = rA & 7;
      f32x4 a0 = *(const f32x4*)&a_cur[rA * 32 + (((2 * g) ^ rb) << 2)];
      f32x4 a1 = *(const f32x4*)&a_cur[rA * 32 + (((2 * g + 1) ^ rb) << 2)];
      f32x8 af = __builtin_shufflevector(a0, a1, 0, 1, 2, 3, 4, 5, 6, 7);
      avec[i] = __builtin_convertvector(af, bf16x8);
    }
#pragma unroll
    for (int j = 0; j < 4; ++j)
      bvec[j] = *(const bf16x8*)&b_cur[(wc * 64 + j * 16 + c16) * 32 + g * 8];
#pragma unroll
    for (int i = 0; i < 4; ++i)
#pragma unroll
      for (int j = 0; j < 4; ++j)
        acc[i][j] = __builtin_amdgcn_mfma_f32_16x16x32_bf16(avec[i], bvec[j], acc[i][j], 0, 0, 0);

    float* ta = a_cur; a_cur = a_nxt; a_nxt = ta;
    uint16_t* tb = b_cur; b_cur = b_nxt; b_nxt = tb;
  }

#pragma unroll
  for (int i = 0; i < 4; ++i) {
#pragma unroll
    for (int j = 0; j < 4; ++j) {
      const int col = n0 + wc * 64 + j * 16 + c16;
      if (z == 2) {
        // V^T layout [b*16+h][d][n]; rows g*4+r2 are 4 consecutive n -> 8B store
        const int h = col >> 6, d = col & 63;
        const int row0 = m0 + wr * 64 + i * 16 + g * 4;
        const int b = row0 >> 11, n = row0 & 2047;
        ushort4 o;
        o.x = f2bf(acc[i][j][0]); o.y = f2bf(acc[i][j][1]);
        o.z = f2bf(acc[i][j][2]); o.w = f2bf(acc[i][j][3]);
        *(ushort4*)&Cout[(size_t)2 * M_TOT * 1024 +
                         (((size_t)(b * HEADS + h)) * DH + d) * N_SEQ + n] = o;
      } else {
#pragma unroll
        for (int r2 = 0; r2 < 4; ++r2) {
          const int row = m0 + wr * 64 + i * 16 + g * 4 + r2;
          const int b = row >> 11, n = row & 2047;
          const int h = col >> 6, d = col & 63;
          Cout[(size_t)z * M_TOT * 1024 + (((size_t)(b * HEADS + h)) * N_SEQ + n) * DH + d] =
              f2bf(acc[i][j][r2] * scale);
        }
      }
    }
  }
}

// ---------------- output projection GEMM, double-buffered single-barrier --------
__global__ __launch_bounds__(256, 2) void gemm_out(const uint16_t* __restrict__ A,
                                                   const uint16_t* __restrict__ BT,
                                                   float* __restrict__ Cout,
                                                   const float* __restrict__ bias) {
  __shared__ __align__(16) uint16_t As0[128 * 32];
  __shared__ __align__(16) uint16_t As1[128 * 32];
  __shared__ __align__(16) uint16_t Bs0[128 * 32];
  __shared__ __align__(16) uint16_t Bs1[128 * 32];
  const int tid = threadIdx.x;
  const int wave = tid >> 6, lane = tid & 63;
  const int g = lane >> 4, c16 = lane & 15;

  const int bid = blockIdx.x;
  const int xcd = bid & 7;
  const int l = bid >> 3;
  const int n0 = (l & 7) * 128;
  const int m0 = (xcd * 8 + (l >> 3)) * 128;
  const int wr = wave >> 1, wc = wave & 1;

  const f32x4 fzero = {0.f, 0.f, 0.f, 0.f};
  f32x4 acc[4][4];
#pragma unroll
  for (int i = 0; i < 4; ++i)
#pragma unroll
    for (int j = 0; j < 4; ++j) acc[i][j] = fzero;

  const int srow = wave * 32 + (lane >> 2);
  const int scol = (lane & 3) * 8;
  const uint16_t* ag0 = A + (size_t)(m0 + srow) * K_DIM + scol;
  const uint16_t* ag1 = A + (size_t)(m0 + srow + 16) * K_DIM + scol;
  const uint16_t* bg0 = BT + (size_t)(n0 + srow) * K_DIM + scol;
  const uint16_t* bg1 = BT + (size_t)(n0 + srow + 16) * K_DIM + scol;
  const int lo0 = (wave * 32) * 32;
  const int lo1 = (wave * 32 + 16) * 32;

  // prologue: tile 0 -> buffer 0
  gld_lds16(ag0, As0 + lo0);
  gld_lds16(ag1, As0 + lo1);
  gld_lds16(bg0, Bs0 + lo0);
  gld_lds16(bg1, Bs0 + lo1);

  uint16_t* a_cur = As0;
  uint16_t* a_nxt = As1;
  uint16_t* b_cur = Bs0;
  uint16_t* b_nxt = Bs1;

  for (int kt = 0; kt < K_DIM / 32; ++kt) {
    __syncthreads();
    if (kt + 1 < K_DIM / 32) {
      const int ko = (kt + 1) * 32;
      gld_lds16(ag0 + ko, a_nxt + lo0);
      gld_lds16(ag1 + ko, a_nxt + lo1);
      gld_lds16(bg0 + ko, b_nxt + lo0);
      gld_lds16(bg1 + ko, b_nxt + lo1);
    }
    bf16x8 avec[4], bvec[4];
#pragma unroll
    for (int i = 0; i < 4; ++i)
      avec[i] = *(const bf16x8*)&a_cur[(wr * 64 + i * 16 + c16) * 32 + g * 8];
#pragma unroll
    for (int j = 0; j < 4; ++j)
      bvec[j] = *(const bf16x8*)&b_cur[(wc * 64 + j * 16 + c16) * 32 + g * 8];
#pragma unroll
    for (int i = 0; i < 4; ++i)
#pragma unroll
      for (int j = 0; j < 4; ++j)
        acc[i][j] = __builtin_amdgcn_mfma_f32_16x16x32_bf16(avec[i], bvec[j], acc[i][j], 0, 0, 0);

    uint16_t* t;
    t = a_cur; a_cur = a_nxt; a_nxt = t;
    t = b_cur; b_cur = b_nxt; b_nxt = t;
  }

#pragma unroll
  for (int i = 0; i < 4; ++i) {
#pragma unroll
    for (int j = 0; j < 4; ++j) {
      const int col = n0 + wc * 64 + j * 16 + c16;
#pragma unroll
      for (int r2 = 0; r2 < 4; ++r2) {
        const int row = m0 + wr * 64 + i * 16 + g * 4 + r2;
        Cout[(size_t)row * 1024 + col] = acc[i][j][r2] + bias[col];
      }
    }
  }
}

// ---------------- flash attention (R6 known-good) ----------------
// NOTE: __launch_bounds__(256,2) — do NOT tighten; (256,4) caps VGPR at 128 and
// spills the accumulators (R7: 3 GB scratch traffic, 7.8x regression).
__global__ __launch_bounds__(256, 2) void attention_k(const uint16_t* __restrict__ qm,
                                                      const uint16_t* __restrict__ km,
                                                      const uint16_t* __restrict__ vtm,
                                                      uint16_t* __restrict__ om) {
  __shared__ __align__(16) uint16_t Ks[64 * 64];
  __shared__ __align__(16) uint16_t Vs[64 * 64];
  const int tid = threadIdx.x;
  const int wave = tid >> 6, lane = tid & 63;
  const int g = lane >> 4, c16 = lane & 15;

  const int bid = blockIdx.x;
  const int xcd = bid & 7;
  const int l0 = bid >> 3;
  const int bh = xcd * 8 + (l0 & 7);
  const int qblk = l0 >> 3;
  const int b = bh >> 4, h = bh & 15;
  const int q0 = qblk * 256 + wave * 64;

  const uint16_t* qbase = qm + (size_t)bh * N_SEQ * DH;
  const uint16_t* kbase = km + (size_t)bh * N_SEQ * DH;
  const uint16_t* vbase = vtm + (size_t)bh * DH * N_SEQ;

  bf16x8 qf[4][2];
#pragma unroll
  for (int qc = 0; qc < 4; ++qc) {
    const uint16_t* qp = qbase + (size_t)(q0 + qc * 16 + c16) * DH + g * 8;
    qf[qc][0] = *(const bf16x8*)qp;
    qf[qc][1] = *(const bf16x8*)(qp + 32);
  }

  const f32x4 fz = {0.f, 0.f, 0.f, 0.f};
  f32x4 oacc[4][4];
#pragma unroll
  for (int qc = 0; qc < 4; ++qc)
#pragma unroll
    for (int jt = 0; jt < 4; ++jt) oacc[qc][jt] = fz;
  float l[4] = {0.f, 0.f, 0.f, 0.f};

  const int sw = c16 & 7;

  const int ch = tid & 7;
  const int krow0 = tid >> 3, krow1 = (256 + tid) >> 3;
  const int kdst0 = krow0 * 64 + ((ch ^ (krow0 & 7)) << 3);
  const int kdst1 = krow1 * 64 + ((ch ^ (krow1 & 7)) << 3);

  uint4 kp0, kp1, vp0, vp1;
  kp0 = *(const uint4*)&kbase[(size_t)tid * 8];
  kp1 = *(const uint4*)&kbase[(size_t)(256 + tid) * 8];
  vp0 = *(const uint4*)&vbase[(size_t)krow0 * N_SEQ + ch * 8];
  vp1 = *(const uint4*)&vbase[(size_t)krow1 * N_SEQ + ch * 8];
  *(uint4*)&Ks[kdst0] = kp0;
  *(uint4*)&Ks[kdst1] = kp1;
  *(uint4*)&Vs[kdst0] = vp0;
  *(uint4*)&Vs[kdst1] = vp1;
  __syncthreads();

  for (int t = 0; t < N_SEQ / 64; ++t) {
    if (t < N_SEQ / 64 - 1) {
      const size_t ko = (size_t)(t + 1) * 4096;
      const int vc = (t + 1) * 64;
      kp0 = *(const uint4*)&kbase[ko + (size_t)tid * 8];
      kp1 = *(const uint4*)&kbase[ko + (size_t)(256 + tid) * 8];
      vp0 = *(const uint4*)&vbase[(size_t)krow0 * N_SEQ + vc + ch * 8];
      vp1 = *(const uint4*)&vbase[(size_t)krow1 * N_SEQ + vc + ch * 8];
    }

#pragma unroll
    for (int kt = 0; kt < 4; ++kt) {
      const int krow = kt * 16 + c16;
      bf16x8 kf0 = *(const bf16x8*)&Ks[krow * 64 + ((g ^ sw) << 3)];
      bf16x8 kf1 = *(const bf16x8*)&Ks[krow * 64 + (((4 + g) ^ sw) << 3)];
      bf16x4 pk[4];
#pragma unroll
      for (int qc = 0; qc < 4; ++qc) {
        f32x4 z = fz;
        z = __builtin_amdgcn_mfma_f32_16x16x32_bf16(kf0, qf[qc][0], z, 0, 0, 0);
        z = __builtin_amdgcn_mfma_f32_16x16x32_bf16(kf1, qf[qc][1], z, 0, 0, 0);
        f32x4 pv;
        pv[0] = __builtin_amdgcn_exp2f(z[0]);
        pv[1] = __builtin_amdgcn_exp2f(z[1]);
        pv[2] = __builtin_amdgcn_exp2f(z[2]);
        pv[3] = __builtin_amdgcn_exp2f(z[3]);
        l[qc] += (pv[0] + pv[1]) + (pv[2] + pv[3]);
        pk[qc] = __builtin_convertvector(pv, bf16x4);
      }
#pragma unroll
      for (int jt = 0; jt < 4; ++jt) {
        bf16x4 vb = *(const bf16x4*)&Vs[(jt * 16 + c16) * 64 +
                                        (((kt * 2 + (g >> 1)) ^ sw) << 3) + (g & 1) * 4];
#pragma unroll
        for (int qc = 0; qc < 4; ++qc) oacc[qc][jt] = mfma16(pk[qc], vb, oacc[qc][jt]);
      }
    }

    if (t < N_SEQ / 64 - 1) {
      __syncthreads();
      *(uint4*)&Ks[kdst0] = kp0;
      *(uint4*)&Ks[kdst1] = kp1;
      *(uint4*)&Vs[kdst0] = vp0;
      *(uint4*)&Vs[kdst1] = vp1;
      __syncthreads();
    }
  }

#pragma unroll
  for (int qc = 0; qc < 4; ++qc) {
    l[qc] += __shfl_xor(l[qc], 16);
    l[qc] += __shfl_xor(l[qc], 32);
  }

#pragma unroll
  for (int qc = 0; qc < 4; ++qc) {
#pragma unroll
    for (int r = 0; r < 4; ++r) {
      const float lr = __shfl(l[qc], g * 4 + r, 16);
      const float inv = 1.f / lr;
      const int row = q0 + qc * 16 + g * 4 + r;
      const size_t base = ((size_t)b * N_SEQ + row) * 1024 + h * 64;
#pragma unroll
      for (int jt = 0; jt < 4; ++jt)
        om[base + jt * 16 + c16] = f2bf(oacc[qc][jt][r] * inv);
    }
  }
}

// ---------------- LayerNorm + residual ----------------
__global__ __launch_bounds__(256) void ln_res_k(const float* __restrict__ proj,
                                                const float* __restrict__ query,
                                                const float* __restrict__ gamma,
                                                const float* __restrict__ beta,
                                                float* __restrict__ out) {
  const int row = blockIdx.x;
  const int tid = threadIdx.x;
  const size_t base = (size_t)row * 1024 + tid * 4;
  float4 v = *(const float4*)(proj + base);
  float s = v.x + v.y + v.z + v.w;
  float s2 = v.x * v.x + v.y * v.y + v.z * v.z + v.w * v.w;
#pragma unroll
  for (int off = 1; off < 64; off <<= 1) {
    s += __shfl_xor(s, off);
    s2 += __shfl_xor(s2, off);
  }
  __shared__ float red[8];
  const int wave = tid >> 6, lane = tid & 63;
  if (lane == 0) { red[wave] = s; red[4 + wave] = s2; }
  __syncthreads();
  s = red[0] + red[1] + red[2] + red[3];
  s2 = red[4] + red[5] + red[6] + red[7];
  const float mu = s * (1.f / 1024.f);
  const float var = fmaxf(s2 * (1.f / 1024.f) - mu * mu, 0.f);
  const float rstd = rsqrtf(var + 1e-5f);
  float4 gq = *(const float4*)(gamma + tid * 4);
  float4 bq = *(const float4*)(beta + tid * 4);
  float4 qq = *(const float4*)(query + base);
  float4 o;
  o.x = (v.x - mu) * rstd * gq.x + bq.x + qq.x;
  o.y = (v.y - mu) * rstd * gq.y + bq.y + qq.y;
  o.z = (v.z - mu) * rstd * gq.z + bq.z + qq.z;
  o.w = (v.w - mu) * rstd * gq.w + bq.w + qq.w;
  *(float4*)(out + base) = o;
}

extern "C" void kernel_launch(void* const* d_in, const int* in_sizes, int n_in,
                              void* d_out, int out_size, void* d_ws, size_t ws_size,
                              hipStream_t stream) {
  (void)in_sizes; (void)n_in; (void)out_size; (void)ws_size;
  const float* query = (const float*)d_in[0];
  const float* key_ = (const float*)d_in[1];
  const float* value = (const float*)d_in[2];
  const float* Wq = (const float*)d_in[3];
  const float* Wk = (const float*)d_in[4];
  const float* Wv = (const float*)d_in[5];
  const float* Wo = (const float*)d_in[6];
  const float* bo = (const float*)d_in[7];
  const float* gamma = (const float*)d_in[8];
  const float* beta = (const float*)d_in[9];
  float* out = (float*)d_out;

  const size_t NELEM = (size_t)M_TOT * 1024;  // 8388608
  uint16_t* wsp = (uint16_t*)d_ws;
  uint16_t* WqT = wsp;                    // 4 x 1M bf16 (Wq,Wk,Wv,Wo contiguous)
  uint16_t* WoT = WqT + 3 * 1024 * 1024;
  uint16_t* qb = wsp + 4 * 1024 * 1024;   // qb,kb,vt contiguous (z * NELEM)
  uint16_t* attnO = qb + 3 * NELEM;       // bf16 [B,N,1024]
  float* proj = (float*)(attnO + NELEM);  // fp32 [M,1024]

  transpose_conv<<<dim3(32, 32, 4), dim3(32, 8), 0, stream>>>(Wq, Wk, Wv, Wo, WqT);

  gemm_qkv<<<1536, 256, 0, stream>>>(query, key_, value, WqT, qb);

  attention_k<<<512, 256, 0, stream>>>(qb, qb + NELEM, qb + 2 * NELEM, attnO);

  gemm_out<<<512, 256, 0, stream>>>(attnO, WoT, proj, bo);

  ln_res_k<<<8192, 256, 0, stream>>>(proj, query, gamma, beta, out);
}